// Round 4
// baseline (415.133 us; speedup 1.0000x reference)
//
#include <hip/hip_runtime.h>
#include <math.h>

#define NN    4096
#define DCC   14
#define KCATN 336
#define KXP   384      // [cont 0..13][pad..31][cat 32..367][pad..383]
#define DF    512
#define NT    64       // 4096 / 64 tiles per dim
#define NTRI  2080     // NT*(NT+1)/2

typedef __attribute__((ext_vector_type(4))) float f32x4;
typedef __attribute__((ext_vector_type(8))) short short8;
typedef unsigned short ushort_t;

__device__ __forceinline__ f32x4 mfma16(short8 a, short8 b, f32x4 c) {
  return __builtin_amdgcn_mfma_f32_16x16x32_bf16(a, b, c, 0, 0, 0);
}
__device__ __forceinline__ short8 ld8(const ushort_t* p) {
  return *(const short8*)p;
}
__device__ __forceinline__ ushort_t f2bf(float x) {
  unsigned u = __float_as_uint(x);
  return (ushort_t)((u + 0x7fffu + ((u >> 16) & 1u)) >> 16);
}
__device__ __forceinline__ float bf2f(ushort_t u) {
  return __uint_as_float(((unsigned)u) << 16);
}
__device__ __forceinline__ float sim_of(float cdot, float kdot, float si, float sj, float invl) {
  float d2 = fmaxf(si + sj - 2.f * cdot, 0.f);
  float cs = 1.0f / (1.0f + sqrtf(d2)) * 2.0f - 1.0f;
  return 0.5f * cs + 0.5f * (kdot * invl);
}

// one K=32 gram step over a 32x32 output: 2x2 frags, split-bf16 (3 MFMA / product)
__device__ __forceinline__ void gram_step32(const ushort_t* pah, const ushort_t* pal,
                                            const ushort_t* pbh, const ushort_t* pbl,
                                            int ldr, int koff, f32x4 (*acc)[2]) {
  short8 ah[2], al[2], bh[2], bl[2];
  #pragma unroll
  for (int f = 0; f < 2; ++f) {
    const int ro = f * 16 * ldr + koff;
    ah[f] = ld8(pah + ro); al[f] = ld8(pal + ro);
    bh[f] = ld8(pbh + ro); bl[f] = ld8(pbl + ro);
  }
  #pragma unroll
  for (int mf = 0; mf < 2; ++mf)
    #pragma unroll
    for (int nf = 0; nf < 2; ++nf) {
      acc[mf][nf] = mfma16(ah[mf], bh[nf], acc[mf][nf]);
      acc[mf][nf] = mfma16(ah[mf], bl[nf], acc[mf][nf]);
      acc[mf][nf] = mfma16(al[mf], bh[nf], acc[mf][nf]);
    }
}

__device__ __forceinline__ void tri_map(int t, int* bip, int* bjp) {
  int bi = 0, rem = t;
  while (rem >= NT - bi) { rem -= NT - bi; ++bi; }
  *bip = bi; *bjp = bi + rem;
}

__global__ __launch_bounds__(64) void prep_kernel(
    const float* __restrict__ feat, const float* __restrict__ cont,
    const float* __restrict__ cat,
    ushort_t* __restrict__ fhh, ushort_t* __restrict__ fhl,
    ushort_t* __restrict__ xch, ushort_t* __restrict__ xcl,
    float* __restrict__ csq, float* __restrict__ rm,
    float* __restrict__ pos, float* __restrict__ den) {
  int i = blockIdx.x;
  int t = threadIdx.x;

  // normalized features -> bf16 hi/lo
  float fv[8];
  float s = 0.f;
  #pragma unroll
  for (int r = 0; r < 8; ++r) { fv[r] = feat[i * DF + r * 64 + t]; s += fv[r] * fv[r]; }
  #pragma unroll
  for (int off = 32; off > 0; off >>= 1) s += __shfl_down(s, off);
  s = __shfl(s, 0);
  float inv = 1.0f / sqrtf(s);
  #pragma unroll
  for (int r = 0; r < 8; ++r) {
    float x = fv[r] * inv;
    ushort_t h = f2bf(x);
    fhh[i * DF + r * 64 + t] = h;
    fhl[i * DF + r * 64 + t] = f2bf(x - bf2f(h));
  }

  // continuous squared norm
  float cv = (t < DCC) ? cont[i * DCC + t] : 0.f;
  float cs = cv * cv;
  #pragma unroll
  for (int off = 32; off > 0; off >>= 1) cs += __shfl_down(cs, off);
  cs = __shfl(cs, 0);

  // padded combined matrix -> bf16 hi/lo
  #pragma unroll
  for (int r = 0; r < 6; ++r) {
    int k = r * 64 + t;
    float v = 0.f;
    if (k < DCC) v = cont[i * DCC + k];
    else if (k >= 32 && k < 32 + KCATN) v = cat[i * KCATN + (k - 32)];
    ushort_t h = f2bf(v);
    xch[i * KXP + k] = h;
    xcl[i * KXP + k] = f2bf(v - bf2f(h));
  }

  if (t == 0) {
    csq[i] = cs;
    rm[i] = 0.f;   // diag sim = 0 -> true rowmax >= 0
    pos[i] = 0.f;
    den[i] = 0.f;
  }
}

// Pass A: sim tiles (triangular, 64x64/block) -> per-row max (row-side + mirrored col-side)
__global__ __launch_bounds__(256, 4) void passA_kernel(
    const ushort_t* __restrict__ xch, const ushort_t* __restrict__ xcl,
    const float* __restrict__ csq, float* __restrict__ rm,
    const int* __restrict__ lcp) {
  int bi, bj; tri_map(blockIdx.x, &bi, &bj);
  const int tid = threadIdx.x;
  const int lane = tid & 63, w = tid >> 6;
  const int wm = w >> 1, wn = w & 1;
  const int l15 = lane & 15, lg = lane >> 4;
  const int i0 = bi * 64 + wm * 32, j0 = bj * 64 + wn * 32;

  const ushort_t* pah = xch + (size_t)(i0 + l15) * KXP + lg * 8;
  const ushort_t* pal = xcl + (size_t)(i0 + l15) * KXP + lg * 8;
  const ushort_t* pbh = xch + (size_t)(j0 + l15) * KXP + lg * 8;
  const ushort_t* pbl = xcl + (size_t)(j0 + l15) * KXP + lg * 8;

  f32x4 accC[2][2], accK[2][2];
  #pragma unroll
  for (int a = 0; a < 2; ++a)
    #pragma unroll
    for (int b = 0; b < 2; ++b) { accC[a][b] = (f32x4){0.f,0.f,0.f,0.f}; accK[a][b] = (f32x4){0.f,0.f,0.f,0.f}; }

  gram_step32(pah, pal, pbh, pbl, KXP, 0, accC);          // cont block (k 0..31)
  #pragma unroll
  for (int kb = 1; kb < 12; ++kb)
    gram_step32(pah, pal, pbh, pbl, KXP, kb * 32, accK);  // cat blocks

  const float invl = 1.0f / (float)(*lcp);
  float csqi[2][4], csqj[2];
  #pragma unroll
  for (int mf = 0; mf < 2; ++mf)
    #pragma unroll
    for (int r = 0; r < 4; ++r) csqi[mf][r] = csq[i0 + mf * 16 + lg * 4 + r];
  #pragma unroll
  for (int nf = 0; nf < 2; ++nf) csqj[nf] = csq[j0 + nf * 16 + l15];

  float rmaxr[2][4], cmax[2];
  #pragma unroll
  for (int mf = 0; mf < 2; ++mf)
    #pragma unroll
    for (int r = 0; r < 4; ++r) rmaxr[mf][r] = -1e30f;
  #pragma unroll
  for (int nf = 0; nf < 2; ++nf) cmax[nf] = -1e30f;

  #pragma unroll
  for (int mf = 0; mf < 2; ++mf)
    #pragma unroll
    for (int nf = 0; nf < 2; ++nf)
      #pragma unroll
      for (int r = 0; r < 4; ++r) {
        int gi = i0 + mf * 16 + lg * 4 + r;
        int gj = j0 + nf * 16 + l15;
        float sim = sim_of(accC[mf][nf][r], accK[mf][nf][r], csqi[mf][r], csqj[nf], invl);
        if (gi == gj) sim = 0.f;
        rmaxr[mf][r] = fmaxf(rmaxr[mf][r], sim);
        cmax[nf] = fmaxf(cmax[nf], sim);
      }

  // row-side: reduce over 16 cols (lanes l15)
  #pragma unroll
  for (int mf = 0; mf < 2; ++mf)
    #pragma unroll
    for (int r = 0; r < 4; ++r) {
      float v = rmaxr[mf][r];
      #pragma unroll
      for (int off = 1; off < 16; off <<= 1) v = fmaxf(v, __shfl_xor(v, off));
      if (l15 == 0) atomicMax((int*)&rm[i0 + mf * 16 + lg * 4 + r], __float_as_int(v));
    }
  // col-side (mirror): reduce over rows (lane groups)
  if (bi != bj) {
    #pragma unroll
    for (int nf = 0; nf < 2; ++nf) {
      float v = cmax[nf];
      v = fmaxf(v, __shfl_xor(v, 16));
      v = fmaxf(v, __shfl_xor(v, 32));
      if (lg == 0) atomicMax((int*)&rm[j0 + nf * 16 + l15], __float_as_int(v));
    }
  }
}

// Pass B: recompute sim -> masks; f-gram -> exp; pos/den (row-side + mirror)
__global__ __launch_bounds__(256, 4) void passB_kernel(
    const ushort_t* __restrict__ xch, const ushort_t* __restrict__ xcl,
    const ushort_t* __restrict__ fhh, const ushort_t* __restrict__ fhl,
    const float* __restrict__ csq, const float* __restrict__ rm,
    float* __restrict__ pos, float* __restrict__ den,
    const int* __restrict__ lcp) {
  int bi, bj; tri_map(blockIdx.x, &bi, &bj);
  const int tid = threadIdx.x;
  const int lane = tid & 63, w = tid >> 6;
  const int wm = w >> 1, wn = w & 1;
  const int l15 = lane & 15, lg = lane >> 4;
  const int i0 = bi * 64 + wm * 32, j0 = bj * 64 + wn * 32;

  // ---- sim grams ----
  const ushort_t* pah = xch + (size_t)(i0 + l15) * KXP + lg * 8;
  const ushort_t* pal = xcl + (size_t)(i0 + l15) * KXP + lg * 8;
  const ushort_t* pbh = xch + (size_t)(j0 + l15) * KXP + lg * 8;
  const ushort_t* pbl = xcl + (size_t)(j0 + l15) * KXP + lg * 8;

  f32x4 accC[2][2], accK[2][2];
  #pragma unroll
  for (int a = 0; a < 2; ++a)
    #pragma unroll
    for (int b = 0; b < 2; ++b) { accC[a][b] = (f32x4){0.f,0.f,0.f,0.f}; accK[a][b] = (f32x4){0.f,0.f,0.f,0.f}; }

  gram_step32(pah, pal, pbh, pbl, KXP, 0, accC);
  #pragma unroll
  for (int kb = 1; kb < 12; ++kb)
    gram_step32(pah, pal, pbh, pbl, KXP, kb * 32, accK);

  const float invl = 1.0f / (float)(*lcp);
  float csqi[2][4], csqj[2], rmi[2][4], rmj[2];
  #pragma unroll
  for (int mf = 0; mf < 2; ++mf)
    #pragma unroll
    for (int r = 0; r < 4; ++r) {
      int gi = i0 + mf * 16 + lg * 4 + r;
      csqi[mf][r] = csq[gi];
      rmi[mf][r] = rm[gi] - 0.05f;
    }
  #pragma unroll
  for (int nf = 0; nf < 2; ++nf) {
    int gj = j0 + nf * 16 + l15;
    csqj[nf] = csq[gj];
    rmj[nf] = rm[gj] - 0.05f;
  }

  unsigned mA = 0, mB = 0;
  #pragma unroll
  for (int mf = 0; mf < 2; ++mf)
    #pragma unroll
    for (int nf = 0; nf < 2; ++nf)
      #pragma unroll
      for (int r = 0; r < 4; ++r) {
        int gi = i0 + mf * 16 + lg * 4 + r;
        int gj = j0 + nf * 16 + l15;
        float sim = sim_of(accC[mf][nf][r], accK[mf][nf][r], csqi[mf][r], csqj[nf], invl);
        if (gi == gj) sim = 0.f;
        unsigned bit = 1u << (mf * 8 + nf * 4 + r);
        if (sim >= rmi[mf][r]) mA |= bit;
        if (sim >= rmj[nf]) mB |= bit;
      }

  // ---- f-gram ----
  const ushort_t* qah = fhh + (size_t)(i0 + l15) * DF + lg * 8;
  const ushort_t* qal = fhl + (size_t)(i0 + l15) * DF + lg * 8;
  const ushort_t* qbh = fhh + (size_t)(j0 + l15) * DF + lg * 8;
  const ushort_t* qbl = fhl + (size_t)(j0 + l15) * DF + lg * 8;

  f32x4 facc[2][2];
  #pragma unroll
  for (int a = 0; a < 2; ++a)
    #pragma unroll
    for (int b = 0; b < 2; ++b) facc[a][b] = (f32x4){0.f,0.f,0.f,0.f};
  #pragma unroll
  for (int kb = 0; kb < 16; ++kb)
    gram_step32(qah, qal, qbh, qbl, DF, kb * 32, facc);

  // ---- epilogue ----
  float posA[2][4], denA[2][4], posB[2], denB[2];
  #pragma unroll
  for (int mf = 0; mf < 2; ++mf)
    #pragma unroll
    for (int r = 0; r < 4; ++r) { posA[mf][r] = 0.f; denA[mf][r] = 0.f; }
  #pragma unroll
  for (int nf = 0; nf < 2; ++nf) { posB[nf] = 0.f; denB[nf] = 0.f; }

  #pragma unroll
  for (int mf = 0; mf < 2; ++mf)
    #pragma unroll
    for (int nf = 0; nf < 2; ++nf)
      #pragma unroll
      for (int r = 0; r < 4; ++r) {
        float e = __expf(facc[mf][nf][r] * 10.0f);
        denA[mf][r] += e;
        denB[nf] += e;
        unsigned bit = 1u << (mf * 8 + nf * 4 + r);
        if (mA & bit) posA[mf][r] += e;
        if (mB & bit) posB[nf] += e;
      }

  #pragma unroll
  for (int mf = 0; mf < 2; ++mf)
    #pragma unroll
    for (int r = 0; r < 4; ++r) {
      float p = posA[mf][r], d = denA[mf][r];
      #pragma unroll
      for (int off = 1; off < 16; off <<= 1) { p += __shfl_xor(p, off); d += __shfl_xor(d, off); }
      if (l15 == 0) {
        int gi = i0 + mf * 16 + lg * 4 + r;
        atomicAdd(&pos[gi], p);
        atomicAdd(&den[gi], d);
      }
    }
  if (bi != bj) {
    #pragma unroll
    for (int nf = 0; nf < 2; ++nf) {
      float p = posB[nf], d = denB[nf];
      p += __shfl_xor(p, 16); d += __shfl_xor(d, 16);
      p += __shfl_xor(p, 32); d += __shfl_xor(d, 32);
      if (lg == 0) {
        int gj = j0 + nf * 16 + l15;
        atomicAdd(&pos[gj], p);
        atomicAdd(&den[gj], d);
      }
    }
  }
}

__global__ __launch_bounds__(256) void reduce_kernel(const float* __restrict__ pos,
                                                     const float* __restrict__ den,
                                                     float* __restrict__ out) {
  __shared__ float sred[4];
  int t = threadIdx.x;
  float s = 0.f;
  for (int i = t; i < NN; i += 256) s += -logf(pos[i] / den[i]);
  #pragma unroll
  for (int off = 32; off > 0; off >>= 1) s += __shfl_down(s, off);
  if ((t & 63) == 0) sred[t >> 6] = s;
  __syncthreads();
  if (t == 0) out[0] = (sred[0] + sred[1] + sred[2] + sred[3]) * (1.0f / NN);
}

extern "C" void kernel_launch(void* const* d_in, const int* in_sizes, int n_in,
                              void* d_out, int out_size, void* d_ws, size_t ws_size,
                              hipStream_t stream) {
  (void)in_sizes; (void)n_in; (void)out_size; (void)ws_size;
  const float* feat = (const float*)d_in[0];
  const float* cont = (const float*)d_in[1];
  const float* cat  = (const float*)d_in[2];
  const int*   lc   = (const int*)d_in[3];
  float* out = (float*)d_out;

  ushort_t* fhh = (ushort_t*)d_ws;
  ushort_t* fhl = fhh + (size_t)NN * DF;
  ushort_t* xch = fhl + (size_t)NN * DF;
  ushort_t* xcl = xch + (size_t)NN * KXP;
  float* csq = (float*)(xcl + (size_t)NN * KXP);
  float* rm  = csq + NN;
  float* pos = rm + NN;
  float* den = pos + NN;

  prep_kernel<<<NN, 64, 0, stream>>>(feat, cont, cat, fhh, fhl, xch, xcl, csq, rm, pos, den);
  passA_kernel<<<NTRI, 256, 0, stream>>>(xch, xcl, csq, rm, lc);
  passB_kernel<<<NTRI, 256, 0, stream>>>(xch, xcl, fhh, fhl, csq, rm, pos, den, lc);
  reduce_kernel<<<1, 256, 0, stream>>>(pos, den, out);
}

// Round 12
// 293.893 us; speedup vs baseline: 1.4125x; 1.4125x over previous
//
#include <hip/hip_runtime.h>
#include <math.h>

#define NN    4096
#define DCC   14
#define KCATN 336
#define KXP   416      // [cont 0..13][pad..31][cat 32..367][ZERO 368..415]
#define DF    512
#define NT    32       // 4096/128 tiles
#define NTRI  528      // NT*(NT+1)/2
#define NCSIM 20       // aug sim chunks: 2 cont + 18 cat
#define NCF   24       // aug f chunks: 3 * 512/64

typedef __attribute__((ext_vector_type(4))) float f32x4;
typedef __attribute__((ext_vector_type(8))) short short8;
typedef unsigned short ushort_t;
typedef unsigned long long u64;

__device__ __forceinline__ f32x4 mfma16(short8 a, short8 b, f32x4 c) {
  return __builtin_amdgcn_mfma_f32_16x16x32_bf16(a, b, c, 0, 0, 0);
}
__device__ __forceinline__ ushort_t f2bf(float x) {
  unsigned u = __float_as_uint(x);
  return (ushort_t)((u + 0x7fffu + ((u >> 16) & 1u)) >> 16);
}
__device__ __forceinline__ float bf2f(ushort_t u) {
  return __uint_as_float(((unsigned)u) << 16);
}
__device__ __forceinline__ float sim_of(float cdot, float kdot, float si, float sj, float invl) {
  float d2 = fmaxf(si + sj - 2.f * cdot, 0.f);
  float cs = 1.0f / (1.0f + sqrtf(d2)) * 2.0f - 1.0f;
  return 0.5f * cs + 0.5f * (kdot * invl);
}

// async 16B global->LDS DMA (dest = wave-uniform base + lane*16)
__device__ __forceinline__ void gload_lds16(const ushort_t* g, ushort_t* l) {
  __builtin_amdgcn_global_load_lds(
      (const __attribute__((address_space(1))) unsigned int*)g,
      (__attribute__((address_space(3))) unsigned int*)l, 16, 0, 0);
}

__device__ __forceinline__ void tri_map(int t, int* bip, int* bjp) {
  int bi = 0, rem = t;
  while (rem >= NT - bi) { rem -= NT - bi; ++bi; }
  *bip = bi; *bjp = bi + rem;
}

// Stage one 128x64 bf16 chunk each of augmented sim A/B streams into LDS.
// LDS linear; swizzle folded into the global source (granule g ^= row&7).
// A aug: [Ch|Cl],[Ch|0], Kh c2-7, Kl c8-13, Kh c14-19
// B aug: [Ch|Ch],[Cl|0], Kh c2-13, Kl c14-19       (zero src = cols 384..415)
__device__ __forceinline__ void stage_sim_chunk(
    int c, int i0b, int j0b,
    const ushort_t* __restrict__ xch, const ushort_t* __restrict__ xcl,
    ushort_t* Ab, ushort_t* Bb, int tid) {
  const int w = tid >> 6, lane = tid & 63;
  const int g = lane & 7, rsub = lane >> 3;
  const int gs = g ^ rsub;           // row&7 == rsub
  const ushort_t* srcA;
  const ushort_t* srcB;
  if (c == 0)      srcA = (gs < 4) ? xch + gs * 8 : xcl + (gs - 4) * 8;
  else if (c == 1) srcA = (gs < 4) ? xch + gs * 8 : xch + 384 + (gs - 4) * 8;
  else if (c < 8)  srcA = xch + 32 + (c - 2) * 64 + gs * 8;
  else if (c < 14) srcA = xcl + 32 + (c - 8) * 64 + gs * 8;
  else             srcA = xch + 32 + (c - 14) * 64 + gs * 8;
  if (c == 0)      srcB = (gs < 4) ? xch + gs * 8 : xch + (gs - 4) * 8;
  else if (c == 1) srcB = (gs < 4) ? xcl + gs * 8 : xch + 384 + (gs - 4) * 8;
  else if (c < 14) srcB = xch + 32 + ((c - 2) % 6) * 64 + gs * 8;
  else             srcB = xcl + 32 + (c - 14) * 64 + gs * 8;
  #pragma unroll
  for (int q = 0; q < 4; ++q) {
    const int row = (w * 4 + q) * 8 + rsub;
    gload_lds16(srcA + (size_t)(i0b + row) * KXP, Ab + (w * 4 + q) * 512);
    gload_lds16(srcB + (size_t)(j0b + row) * KXP, Bb + (w * 4 + q) * 512);
  }
}

// f aug: A = Fh c0-7, Fl c8-15, Fh c16-23 ; B = Fh c0-15, Fl c16-23
__device__ __forceinline__ void stage_f_chunk(
    int c, int i0b, int j0b,
    const ushort_t* __restrict__ fhh, const ushort_t* __restrict__ fhl,
    ushort_t* Ab, ushort_t* Bb, int tid) {
  const int w = tid >> 6, lane = tid & 63;
  const int g = lane & 7, rsub = lane >> 3;
  const int gs = g ^ rsub;
  const ushort_t* baseA = (c < 8) ? fhh + c * 64 : (c < 16) ? fhl + (c - 8) * 64 : fhh + (c - 16) * 64;
  const ushort_t* baseB = (c < 16) ? fhh + (c & 7) * 64 : fhl + (c - 16) * 64;
  #pragma unroll
  for (int q = 0; q < 4; ++q) {
    const int row = (w * 4 + q) * 8 + rsub;
    gload_lds16(baseA + (size_t)(i0b + row) * DF + gs * 8, Ab + (w * 4 + q) * 512);
    gload_lds16(baseB + (size_t)(j0b + row) * DF + gs * 8, Bb + (w * 4 + q) * 512);
  }
}

// one BK=64 chunk of MFMA work for this wave's 64x64 quadrant (4x4 frags)
__device__ __forceinline__ void compute_chunk(const ushort_t* Ab, const ushort_t* Bb,
                                              int wm, int wn, int l15, int lg,
                                              f32x4 acc[4][4]) {
  const int swz = l15 & 7;
  #pragma unroll
  for (int ks = 0; ks < 2; ++ks) {
    short8 a[4], b[4];
    const int gph = ((ks * 4 + lg) ^ swz) * 8;
    #pragma unroll
    for (int mf = 0; mf < 4; ++mf)
      a[mf] = *(const short8*)&Ab[(wm * 64 + mf * 16 + l15) * 64 + gph];
    #pragma unroll
    for (int nf = 0; nf < 4; ++nf)
      b[nf] = *(const short8*)&Bb[(wn * 64 + nf * 16 + l15) * 64 + gph];
    #pragma unroll
    for (int mf = 0; mf < 4; ++mf)
      #pragma unroll
      for (int nf = 0; nf < 4; ++nf)
        acc[mf][nf] = mfma16(a[mf], b[nf], acc[mf][nf]);
  }
}

__global__ __launch_bounds__(64) void prep_kernel(
    const float* __restrict__ feat, const float* __restrict__ cont,
    const float* __restrict__ cat,
    ushort_t* __restrict__ fhh, ushort_t* __restrict__ fhl,
    ushort_t* __restrict__ xch, ushort_t* __restrict__ xcl,
    float* __restrict__ csq, float* __restrict__ rm,
    float* __restrict__ pos, float* __restrict__ den) {
  int i = blockIdx.x;
  int t = threadIdx.x;

  float fv[8];
  float s = 0.f;
  #pragma unroll
  for (int r = 0; r < 8; ++r) { fv[r] = feat[i * DF + r * 64 + t]; s += fv[r] * fv[r]; }
  #pragma unroll
  for (int off = 32; off > 0; off >>= 1) s += __shfl_down(s, off);
  s = __shfl(s, 0);
  float inv = 1.0f / sqrtf(s);
  #pragma unroll
  for (int r = 0; r < 8; ++r) {
    float x = fv[r] * inv;
    ushort_t h = f2bf(x);
    fhh[i * DF + r * 64 + t] = h;
    fhl[i * DF + r * 64 + t] = f2bf(x - bf2f(h));
  }

  float cv = (t < DCC) ? cont[i * DCC + t] : 0.f;
  float cs = cv * cv;
  #pragma unroll
  for (int off = 32; off > 0; off >>= 1) cs += __shfl_down(cs, off);
  cs = __shfl(cs, 0);

  #pragma unroll
  for (int r = 0; r < 7; ++r) {
    int k = r * 64 + t;
    if (k < KXP) {
      float v = 0.f;
      if (k < DCC) v = cont[i * DCC + k];
      else if (k >= 32 && k < 32 + KCATN) v = cat[i * KCATN + (k - 32)];
      ushort_t h = f2bf(v);
      xch[i * KXP + k] = h;
      xcl[i * KXP + k] = f2bf(v - bf2f(h));
    }
  }

  if (t == 0) {
    csq[i] = cs;
    rm[i] = 0.f;   // diag sim = 0 -> true rowmax >= 0
    pos[i] = 0.f;
    den[i] = 0.f;
  }
}

__global__ __launch_bounds__(256, 2) void passA_kernel(
    const ushort_t* __restrict__ xch, const ushort_t* __restrict__ xcl,
    const float* __restrict__ csq, float* __restrict__ rm,
    const int* __restrict__ lcp) {
  __shared__ ushort_t Ab[2][128 * 64];
  __shared__ ushort_t Bb[2][128 * 64];
  int bi, bj; tri_map(blockIdx.x, &bi, &bj);
  const int tid = threadIdx.x;
  const int lane = tid & 63, w = tid >> 6;
  const int wm = w >> 1, wn = w & 1;
  const int l15 = lane & 15, lg = lane >> 4;
  const int i0b = bi * 128, j0b = bj * 128;

  f32x4 accC[4][4], accK[4][4];
  #pragma unroll
  for (int a = 0; a < 4; ++a)
    #pragma unroll
    for (int b = 0; b < 4; ++b) { accC[a][b] = (f32x4){0.f,0.f,0.f,0.f}; accK[a][b] = (f32x4){0.f,0.f,0.f,0.f}; }

  stage_sim_chunk(0, i0b, j0b, xch, xcl, Ab[0], Bb[0], tid);
  __syncthreads();
  for (int c = 0; c < NCSIM; ++c) {
    if (c + 1 < NCSIM)
      stage_sim_chunk(c + 1, i0b, j0b, xch, xcl, Ab[(c + 1) & 1], Bb[(c + 1) & 1], tid);
    if (c < 2) compute_chunk(Ab[c & 1], Bb[c & 1], wm, wn, l15, lg, accC);
    else       compute_chunk(Ab[c & 1], Bb[c & 1], wm, wn, l15, lg, accK);
    __syncthreads();
  }

  const int i0 = i0b + wm * 64, j0 = j0b + wn * 64;
  const float invl = 1.0f / (float)(*lcp);
  float csqi[4][4], csqj[4];
  #pragma unroll
  for (int mf = 0; mf < 4; ++mf)
    #pragma unroll
    for (int r = 0; r < 4; ++r) csqi[mf][r] = csq[i0 + mf * 16 + lg * 4 + r];
  #pragma unroll
  for (int nf = 0; nf < 4; ++nf) csqj[nf] = csq[j0 + nf * 16 + l15];

  float rmaxr[4][4], cmax[4];
  #pragma unroll
  for (int mf = 0; mf < 4; ++mf)
    #pragma unroll
    for (int r = 0; r < 4; ++r) rmaxr[mf][r] = -1e30f;
  #pragma unroll
  for (int nf = 0; nf < 4; ++nf) cmax[nf] = -1e30f;

  #pragma unroll
  for (int mf = 0; mf < 4; ++mf)
    #pragma unroll
    for (int nf = 0; nf < 4; ++nf)
      #pragma unroll
      for (int r = 0; r < 4; ++r) {
        int gi = i0 + mf * 16 + lg * 4 + r;
        int gj = j0 + nf * 16 + l15;
        float sim = sim_of(accC[mf][nf][r], accK[mf][nf][r], csqi[mf][r], csqj[nf], invl);
        if (gi == gj) sim = 0.f;
        rmaxr[mf][r] = fmaxf(rmaxr[mf][r], sim);
        cmax[nf] = fmaxf(cmax[nf], sim);
      }

  #pragma unroll
  for (int mf = 0; mf < 4; ++mf)
    #pragma unroll
    for (int r = 0; r < 4; ++r) {
      float v = rmaxr[mf][r];
      #pragma unroll
      for (int off = 1; off < 16; off <<= 1) v = fmaxf(v, __shfl_xor(v, off));
      if (l15 == 0) atomicMax((int*)&rm[i0 + mf * 16 + lg * 4 + r], __float_as_int(v));
    }
  if (bi != bj) {
    #pragma unroll
    for (int nf = 0; nf < 4; ++nf) {
      float v = cmax[nf];
      v = fmaxf(v, __shfl_xor(v, 16));
      v = fmaxf(v, __shfl_xor(v, 32));
      if (lg == 0) atomicMax((int*)&rm[j0 + nf * 16 + l15], __float_as_int(v));
    }
  }
}

__global__ __launch_bounds__(256, 2) void passB_kernel(
    const ushort_t* __restrict__ xch, const ushort_t* __restrict__ xcl,
    const ushort_t* __restrict__ fhh, const ushort_t* __restrict__ fhl,
    const float* __restrict__ csq, const float* __restrict__ rm,
    float* __restrict__ pos, float* __restrict__ den,
    const int* __restrict__ lcp) {
  __shared__ ushort_t Ab[2][128 * 64];
  __shared__ ushort_t Bb[2][128 * 64];
  int bi, bj; tri_map(blockIdx.x, &bi, &bj);
  const int tid = threadIdx.x;
  const int lane = tid & 63, w = tid >> 6;
  const int wm = w >> 1, wn = w & 1;
  const int l15 = lane & 15, lg = lane >> 4;
  const int i0b = bi * 128, j0b = bj * 128;
  const int i0 = i0b + wm * 64, j0 = j0b + wn * 64;

  f32x4 accC[4][4], accK[4][4];
  #pragma unroll
  for (int a = 0; a < 4; ++a)
    #pragma unroll
    for (int b = 0; b < 4; ++b) { accC[a][b] = (f32x4){0.f,0.f,0.f,0.f}; accK[a][b] = (f32x4){0.f,0.f,0.f,0.f}; }

  stage_sim_chunk(0, i0b, j0b, xch, xcl, Ab[0], Bb[0], tid);
  __syncthreads();
  for (int c = 0; c < NCSIM; ++c) {
    if (c + 1 < NCSIM)
      stage_sim_chunk(c + 1, i0b, j0b, xch, xcl, Ab[(c + 1) & 1], Bb[(c + 1) & 1], tid);
    if (c < 2) compute_chunk(Ab[c & 1], Bb[c & 1], wm, wn, l15, lg, accC);
    else       compute_chunk(Ab[c & 1], Bb[c & 1], wm, wn, l15, lg, accK);
    __syncthreads();
  }

  // issue first f-chunk DMA, hide it under the mask epilogue
  stage_f_chunk(0, i0b, j0b, fhh, fhl, Ab[0], Bb[0], tid);

  const float invl = 1.0f / (float)(*lcp);
  float csqi[4][4], csqj[4], rmi[4][4], rmj[4];
  #pragma unroll
  for (int mf = 0; mf < 4; ++mf)
    #pragma unroll
    for (int r = 0; r < 4; ++r) {
      int gi = i0 + mf * 16 + lg * 4 + r;
      csqi[mf][r] = csq[gi];
      rmi[mf][r] = rm[gi] - 0.05f;
    }
  #pragma unroll
  for (int nf = 0; nf < 4; ++nf) {
    int gj = j0 + nf * 16 + l15;
    csqj[nf] = csq[gj];
    rmj[nf] = rm[gj] - 0.05f;
  }

  u64 mA = 0, mB = 0;
  #pragma unroll
  for (int mf = 0; mf < 4; ++mf)
    #pragma unroll
    for (int nf = 0; nf < 4; ++nf)
      #pragma unroll
      for (int r = 0; r < 4; ++r) {
        int gi = i0 + mf * 16 + lg * 4 + r;
        int gj = j0 + nf * 16 + l15;
        float sim = sim_of(accC[mf][nf][r], accK[mf][nf][r], csqi[mf][r], csqj[nf], invl);
        if (gi == gj) sim = 0.f;
        u64 bit = 1ull << (mf * 16 + nf * 4 + r);
        if (sim >= rmi[mf][r]) mA |= bit;
        if (sim >= rmj[nf]) mB |= bit;
      }

  __syncthreads();   // f-chunk 0 DMA drained, safe to compute
  f32x4 facc[4][4];
  #pragma unroll
  for (int a = 0; a < 4; ++a)
    #pragma unroll
    for (int b = 0; b < 4; ++b) facc[a][b] = (f32x4){0.f,0.f,0.f,0.f};
  for (int c = 0; c < NCF; ++c) {
    if (c + 1 < NCF)
      stage_f_chunk(c + 1, i0b, j0b, fhh, fhl, Ab[(c + 1) & 1], Bb[(c + 1) & 1], tid);
    compute_chunk(Ab[c & 1], Bb[c & 1], wm, wn, l15, lg, facc);
    __syncthreads();
  }

  float posA[4][4], denA[4][4], posB[4], denB[4];
  #pragma unroll
  for (int mf = 0; mf < 4; ++mf)
    #pragma unroll
    for (int r = 0; r < 4; ++r) { posA[mf][r] = 0.f; denA[mf][r] = 0.f; }
  #pragma unroll
  for (int nf = 0; nf < 4; ++nf) { posB[nf] = 0.f; denB[nf] = 0.f; }

  #pragma unroll
  for (int mf = 0; mf < 4; ++mf)
    #pragma unroll
    for (int nf = 0; nf < 4; ++nf)
      #pragma unroll
      for (int r = 0; r < 4; ++r) {
        float e = __expf(facc[mf][nf][r] * 10.0f);
        denA[mf][r] += e;
        denB[nf] += e;
        u64 bit = 1ull << (mf * 16 + nf * 4 + r);
        if (mA & bit) posA[mf][r] += e;
        if (mB & bit) posB[nf] += e;
      }

  #pragma unroll
  for (int mf = 0; mf < 4; ++mf)
    #pragma unroll
    for (int r = 0; r < 4; ++r) {
      float p = posA[mf][r], d = denA[mf][r];
      #pragma unroll
      for (int off = 1; off < 16; off <<= 1) { p += __shfl_xor(p, off); d += __shfl_xor(d, off); }
      if (l15 == 0) {
        int gi = i0 + mf * 16 + lg * 4 + r;
        atomicAdd(&pos[gi], p);
        atomicAdd(&den[gi], d);
      }
    }
  if (bi != bj) {
    #pragma unroll
    for (int nf = 0; nf < 4; ++nf) {
      float p = posB[nf], d = denB[nf];
      p += __shfl_xor(p, 16); d += __shfl_xor(d, 16);
      p += __shfl_xor(p, 32); d += __shfl_xor(d, 32);
      if (lg == 0) {
        int gj = j0 + nf * 16 + l15;
        atomicAdd(&pos[gj], p);
        atomicAdd(&den[gj], d);
      }
    }
  }
}

__global__ __launch_bounds__(256) void reduce_kernel(const float* __restrict__ pos,
                                                     const float* __restrict__ den,
                                                     float* __restrict__ out) {
  __shared__ float sred[4];
  int t = threadIdx.x;
  float s = 0.f;
  for (int i = t; i < NN; i += 256) s += -logf(pos[i] / den[i]);
  #pragma unroll
  for (int off = 32; off > 0; off >>= 1) s += __shfl_down(s, off);
  if ((t & 63) == 0) sred[t >> 6] = s;
  __syncthreads();
  if (t == 0) out[0] = (sred[0] + sred[1] + sred[2] + sred[3]) * (1.0f / NN);
}

extern "C" void kernel_launch(void* const* d_in, const int* in_sizes, int n_in,
                              void* d_out, int out_size, void* d_ws, size_t ws_size,
                              hipStream_t stream) {
  (void)in_sizes; (void)n_in; (void)out_size; (void)ws_size;
  const float* feat = (const float*)d_in[0];
  const float* cont = (const float*)d_in[1];
  const float* cat  = (const float*)d_in[2];
  const int*   lc   = (const int*)d_in[3];
  float* out = (float*)d_out;

  // ws: fh hi/lo (2x4096x512x2B) + xc hi/lo (2x4096x416x2B) + 4 vec = ~15.3 MB
  ushort_t* fhh = (ushort_t*)d_ws;
  ushort_t* fhl = fhh + (size_t)NN * DF;
  ushort_t* xch = fhl + (size_t)NN * DF;
  ushort_t* xcl = xch + (size_t)NN * KXP;
  float* csq = (float*)(xcl + (size_t)NN * KXP);
  float* rm  = csq + NN;
  float* pos = rm + NN;
  float* den = pos + NN;

  prep_kernel<<<NN, 64, 0, stream>>>(feat, cont, cat, fhh, fhl, xch, xcl, csq, rm, pos, den);
  passA_kernel<<<NTRI, 256, 0, stream>>>(xch, xcl, csq, rm, lc);
  passB_kernel<<<NTRI, 256, 0, stream>>>(xch, xcl, fhh, fhl, csq, rm, pos, den, lc);
  reduce_kernel<<<1, 256, 0, stream>>>(pos, den, out);
}

// Round 13
// 222.538 us; speedup vs baseline: 1.8654x; 1.3206x over previous
//
#include <hip/hip_runtime.h>
#include <math.h>

#define NN    4096
#define DCC   14
#define KCATN 336
#define KXP   416      // [cont 0..13][pad..31][cat 32..367][ZERO 368..415]
#define DF    512
#define NT    32       // 4096/128 tiles
#define NTRI  528      // NT*(NT+1)/2
#define NCSIM 20       // aug sim chunks: 2 cont + 18 cat
#define NCF   24       // aug f chunks: 3 * 512/64

typedef __attribute__((ext_vector_type(4))) float f32x4;
typedef __attribute__((ext_vector_type(8))) short short8;
typedef unsigned short ushort_t;
typedef unsigned long long u64;

__device__ __forceinline__ f32x4 mfma16(short8 a, short8 b, f32x4 c) {
  return __builtin_amdgcn_mfma_f32_16x16x32_bf16(a, b, c, 0, 0, 0);
}
__device__ __forceinline__ ushort_t f2bf(float x) {
  unsigned u = __float_as_uint(x);
  return (ushort_t)((u + 0x7fffu + ((u >> 16) & 1u)) >> 16);
}
__device__ __forceinline__ float bf2f(ushort_t u) {
  return __uint_as_float(((unsigned)u) << 16);
}
__device__ __forceinline__ float sim_of(float cdot, float kdot, float si, float sj, float invl) {
  float d2 = fmaxf(si + sj - 2.f * cdot, 0.f);
  float cs = 1.0f / (1.0f + sqrtf(d2)) * 2.0f - 1.0f;
  return 0.5f * cs + 0.5f * (kdot * invl);
}

// async 16B global->LDS DMA (dest = wave-uniform base + lane*16)
__device__ __forceinline__ void gload_lds16(const ushort_t* g, ushort_t* l) {
  __builtin_amdgcn_global_load_lds(
      (const __attribute__((address_space(1))) unsigned int*)g,
      (__attribute__((address_space(3))) unsigned int*)l, 16, 0, 0);
}

// XCD-contiguous (528 = 8*66, bijective) + 4x4-tile-region ordering:
// each region's A+B panels (~3.8MB) fit one XCD's 4MB L2.
__device__ __forceinline__ void tile_map(int b, int* bip, int* bjp) {
  int t = (b & 7) * 66 + (b >> 3);   // XCD x owns contiguous region-ordered range
  int RI = 0, rem = t;
  for (; RI < 8; ++RI) {
    int rowcnt = 10 + 16 * (7 - RI); // diag region (10 tiles) + off-diag (16 each)
    if (rem < rowcnt) break;
    rem -= rowcnt;
  }
  if (rem < 10) {                    // diagonal 4x4-tri region
    int si = 0;
    while (rem >= 4 - si) { rem -= 4 - si; ++si; }
    *bip = RI * 4 + si; *bjp = RI * 4 + si + rem;
  } else {
    rem -= 10;
    int RJ = RI + 1 + (rem >> 4);
    int w = rem & 15;
    *bip = RI * 4 + (w >> 2); *bjp = RJ * 4 + (w & 3);
  }
}

// Stage one 128x64 bf16 chunk each of augmented sim A/B streams into LDS.
// A aug: [Ch|Cl],[Ch|0], Kh c2-7, Kl c8-13, Kh c14-19
// B aug: [Ch|Ch],[Cl|0], Kh c2-13, Kl c14-19       (zero src = cols 384..415)
__device__ __forceinline__ void stage_sim_chunk(
    int c, int i0b, int j0b,
    const ushort_t* __restrict__ xch, const ushort_t* __restrict__ xcl,
    ushort_t* Ab, ushort_t* Bb, int tid) {
  const int w = tid >> 6, lane = tid & 63;
  const int g = lane & 7, rsub = lane >> 3;
  const int gs = g ^ rsub;           // swizzle folded into global source
  const ushort_t* srcA;
  const ushort_t* srcB;
  if (c == 0)      srcA = (gs < 4) ? xch + gs * 8 : xcl + (gs - 4) * 8;
  else if (c == 1) srcA = (gs < 4) ? xch + gs * 8 : xch + 384 + (gs - 4) * 8;
  else if (c < 8)  srcA = xch + 32 + (c - 2) * 64 + gs * 8;
  else if (c < 14) srcA = xcl + 32 + (c - 8) * 64 + gs * 8;
  else             srcA = xch + 32 + (c - 14) * 64 + gs * 8;
  if (c == 0)      srcB = (gs < 4) ? xch + gs * 8 : xch + (gs - 4) * 8;
  else if (c == 1) srcB = (gs < 4) ? xcl + gs * 8 : xch + 384 + (gs - 4) * 8;
  else if (c < 14) srcB = xch + 32 + ((c - 2) % 6) * 64 + gs * 8;
  else             srcB = xcl + 32 + (c - 14) * 64 + gs * 8;
  #pragma unroll
  for (int q = 0; q < 4; ++q) {
    const int row = (w * 4 + q) * 8 + rsub;
    gload_lds16(srcA + (size_t)(i0b + row) * KXP, Ab + (w * 4 + q) * 512);
    gload_lds16(srcB + (size_t)(j0b + row) * KXP, Bb + (w * 4 + q) * 512);
  }
}

// f aug: A = Fh c0-7, Fl c8-15, Fh c16-23 ; B = Fh c0-15, Fl c16-23
__device__ __forceinline__ void stage_f_chunk(
    int c, int i0b, int j0b,
    const ushort_t* __restrict__ fhh, const ushort_t* __restrict__ fhl,
    ushort_t* Ab, ushort_t* Bb, int tid) {
  const int w = tid >> 6, lane = tid & 63;
  const int g = lane & 7, rsub = lane >> 3;
  const int gs = g ^ rsub;
  const ushort_t* baseA = (c < 8) ? fhh + c * 64 : (c < 16) ? fhl + (c - 8) * 64 : fhh + (c - 16) * 64;
  const ushort_t* baseB = (c < 16) ? fhh + (c & 7) * 64 : fhl + (c - 16) * 64;
  #pragma unroll
  for (int q = 0; q < 4; ++q) {
    const int row = (w * 4 + q) * 8 + rsub;
    gload_lds16(baseA + (size_t)(i0b + row) * DF + gs * 8, Ab + (w * 4 + q) * 512);
    gload_lds16(baseB + (size_t)(j0b + row) * DF + gs * 8, Bb + (w * 4 + q) * 512);
  }
}

// one BK=64 chunk of MFMA work for this wave's 64x64 quadrant (4x4 frags)
__device__ __forceinline__ void compute_chunk(const ushort_t* Ab, const ushort_t* Bb,
                                              int wm, int wn, int l15, int lg,
                                              f32x4 acc[4][4]) {
  const int swz = l15 & 7;
  #pragma unroll
  for (int ks = 0; ks < 2; ++ks) {
    short8 a[4], b[4];
    const int gph = ((ks * 4 + lg) ^ swz) * 8;
    #pragma unroll
    for (int mf = 0; mf < 4; ++mf)
      a[mf] = *(const short8*)&Ab[(wm * 64 + mf * 16 + l15) * 64 + gph];
    #pragma unroll
    for (int nf = 0; nf < 4; ++nf)
      b[nf] = *(const short8*)&Bb[(wn * 64 + nf * 16 + l15) * 64 + gph];
    #pragma unroll
    for (int mf = 0; mf < 4; ++mf)
      #pragma unroll
      for (int nf = 0; nf < 4; ++nf)
        acc[mf][nf] = mfma16(a[mf], b[nf], acc[mf][nf]);
  }
}

__global__ __launch_bounds__(64) void prep_kernel(
    const float* __restrict__ feat, const float* __restrict__ cont,
    const float* __restrict__ cat,
    ushort_t* __restrict__ fhh, ushort_t* __restrict__ fhl,
    ushort_t* __restrict__ xch, ushort_t* __restrict__ xcl,
    float* __restrict__ csq, float* __restrict__ rm,
    float* __restrict__ pos, float* __restrict__ den) {
  int i = blockIdx.x;
  int t = threadIdx.x;

  float fv[8];
  float s = 0.f;
  #pragma unroll
  for (int r = 0; r < 8; ++r) { fv[r] = feat[i * DF + r * 64 + t]; s += fv[r] * fv[r]; }
  #pragma unroll
  for (int off = 32; off > 0; off >>= 1) s += __shfl_down(s, off);
  s = __shfl(s, 0);
  float inv = 1.0f / sqrtf(s);
  #pragma unroll
  for (int r = 0; r < 8; ++r) {
    float x = fv[r] * inv;
    ushort_t h = f2bf(x);
    fhh[i * DF + r * 64 + t] = h;
    fhl[i * DF + r * 64 + t] = f2bf(x - bf2f(h));
  }

  float cv = (t < DCC) ? cont[i * DCC + t] : 0.f;
  float cs = cv * cv;
  #pragma unroll
  for (int off = 32; off > 0; off >>= 1) cs += __shfl_down(cs, off);
  cs = __shfl(cs, 0);

  #pragma unroll
  for (int r = 0; r < 7; ++r) {
    int k = r * 64 + t;
    if (k < KXP) {
      float v = 0.f;
      if (k < DCC) v = cont[i * DCC + k];
      else if (k >= 32 && k < 32 + KCATN) v = cat[i * KCATN + (k - 32)];
      ushort_t h = f2bf(v);
      xch[i * KXP + k] = h;
      xcl[i * KXP + k] = f2bf(v - bf2f(h));
    }
  }

  if (t == 0) {
    csq[i] = cs;
    rm[i] = 0.f;   // diag sim = 0 -> true rowmax >= 0
    pos[i] = 0.f;
    den[i] = 0.f;
  }
}

// Kernel 1: sim gram once -> rowmax atomics + store zeroed-diag sim tile to ws
__global__ __launch_bounds__(256, 2) void simmax_kernel(
    const ushort_t* __restrict__ xch, const ushort_t* __restrict__ xcl,
    const float* __restrict__ csq, float* __restrict__ rm,
    float* __restrict__ simbuf, const int* __restrict__ lcp) {
  __shared__ ushort_t Ab[2][128 * 64];
  __shared__ ushort_t Bb[2][128 * 64];
  int bi, bj; tile_map(blockIdx.x, &bi, &bj);
  const int tid = threadIdx.x;
  const int lane = tid & 63, w = tid >> 6;
  const int wm = w >> 1, wn = w & 1;
  const int l15 = lane & 15, lg = lane >> 4;
  const int i0b = bi * 128, j0b = bj * 128;

  f32x4 accC[4][4], accK[4][4];
  #pragma unroll
  for (int a = 0; a < 4; ++a)
    #pragma unroll
    for (int b = 0; b < 4; ++b) { accC[a][b] = (f32x4){0.f,0.f,0.f,0.f}; accK[a][b] = (f32x4){0.f,0.f,0.f,0.f}; }

  stage_sim_chunk(0, i0b, j0b, xch, xcl, Ab[0], Bb[0], tid);
  __syncthreads();
  for (int c = 0; c < NCSIM; ++c) {
    if (c + 1 < NCSIM)
      stage_sim_chunk(c + 1, i0b, j0b, xch, xcl, Ab[(c + 1) & 1], Bb[(c + 1) & 1], tid);
    if (c < 2) compute_chunk(Ab[c & 1], Bb[c & 1], wm, wn, l15, lg, accC);
    else       compute_chunk(Ab[c & 1], Bb[c & 1], wm, wn, l15, lg, accK);
    __syncthreads();
  }

  const int i0 = i0b + wm * 64, j0 = j0b + wn * 64;
  const float invl = 1.0f / (float)(*lcp);
  float csqi[4][4], csqj[4];
  #pragma unroll
  for (int mf = 0; mf < 4; ++mf)
    #pragma unroll
    for (int r = 0; r < 4; ++r) csqi[mf][r] = csq[i0 + mf * 16 + lg * 4 + r];
  #pragma unroll
  for (int nf = 0; nf < 4; ++nf) csqj[nf] = csq[j0 + nf * 16 + l15];

  float rmaxr[4][4], cmax[4];
  #pragma unroll
  for (int mf = 0; mf < 4; ++mf)
    #pragma unroll
    for (int r = 0; r < 4; ++r) rmaxr[mf][r] = -1e30f;
  #pragma unroll
  for (int nf = 0; nf < 4; ++nf) cmax[nf] = -1e30f;

  #pragma unroll
  for (int mf = 0; mf < 4; ++mf)
    #pragma unroll
    for (int nf = 0; nf < 4; ++nf)
      #pragma unroll
      for (int r = 0; r < 4; ++r) {
        int gi = i0 + mf * 16 + lg * 4 + r;
        int gj = j0 + nf * 16 + l15;
        float sim = sim_of(accC[mf][nf][r], accK[mf][nf][r], csqi[mf][r], csqj[nf], invl);
        if (gi == gj) sim = 0.f;
        rmaxr[mf][r] = fmaxf(rmaxr[mf][r], sim);
        cmax[nf] = fmaxf(cmax[nf], sim);
        accC[mf][nf][r] = sim;   // reuse accC as sim holder for the store
      }

  #pragma unroll
  for (int mf = 0; mf < 4; ++mf)
    #pragma unroll
    for (int r = 0; r < 4; ++r) {
      float v = rmaxr[mf][r];
      #pragma unroll
      for (int off = 1; off < 16; off <<= 1) v = fmaxf(v, __shfl_xor(v, off));
      if (l15 == 0) atomicMax((int*)&rm[i0 + mf * 16 + lg * 4 + r], __float_as_int(v));
    }
  if (bi != bj) {
    #pragma unroll
    for (int nf = 0; nf < 4; ++nf) {
      float v = cmax[nf];
      v = fmaxf(v, __shfl_xor(v, 16));
      v = fmaxf(v, __shfl_xor(v, 32));
      if (lg == 0) atomicMax((int*)&rm[j0 + nf * 16 + l15], __float_as_int(v));
    }
  }

  // store sim tile (thread-slot packed; kernel2 block/thread geometry matches)
  float* slot = simbuf + (size_t)blockIdx.x * 16384 + tid * 64;
  #pragma unroll
  for (int mf = 0; mf < 4; ++mf)
    #pragma unroll
    for (int nf = 0; nf < 4; ++nf)
      *(f32x4*)&slot[mf * 16 + nf * 4] = accC[mf][nf];
}

// Kernel 2: f-gram + stored sim -> masks -> pos/den (row-side + mirror)
__global__ __launch_bounds__(256, 2) void loss_kernel(
    const ushort_t* __restrict__ fhh, const ushort_t* __restrict__ fhl,
    const float* __restrict__ rm, const float* __restrict__ simbuf,
    float* __restrict__ pos, float* __restrict__ den) {
  __shared__ ushort_t Ab[2][128 * 64];
  __shared__ ushort_t Bb[2][128 * 64];
  int bi, bj; tile_map(blockIdx.x, &bi, &bj);
  const int tid = threadIdx.x;
  const int lane = tid & 63, w = tid >> 6;
  const int wm = w >> 1, wn = w & 1;
  const int l15 = lane & 15, lg = lane >> 4;
  const int i0b = bi * 128, j0b = bj * 128;
  const int i0 = i0b + wm * 64, j0 = j0b + wn * 64;

  // issue first f-chunk DMA; hide it under sim reload + mask computation
  stage_f_chunk(0, i0b, j0b, fhh, fhl, Ab[0], Bb[0], tid);

  float rmi[4][4], rmj[4];
  #pragma unroll
  for (int mf = 0; mf < 4; ++mf)
    #pragma unroll
    for (int r = 0; r < 4; ++r) rmi[mf][r] = rm[i0 + mf * 16 + lg * 4 + r] - 0.05f;
  #pragma unroll
  for (int nf = 0; nf < 4; ++nf) rmj[nf] = rm[j0 + nf * 16 + l15] - 0.05f;

  const float* slot = simbuf + (size_t)blockIdx.x * 16384 + tid * 64;
  u64 mA = 0, mB = 0;
  #pragma unroll
  for (int mf = 0; mf < 4; ++mf)
    #pragma unroll
    for (int nf = 0; nf < 4; ++nf) {
      f32x4 sv = *(const f32x4*)&slot[mf * 16 + nf * 4];
      #pragma unroll
      for (int r = 0; r < 4; ++r) {
        u64 bit = 1ull << (mf * 16 + nf * 4 + r);
        if (sv[r] >= rmi[mf][r]) mA |= bit;
        if (sv[r] >= rmj[nf]) mB |= bit;
      }
    }

  __syncthreads();   // f-chunk 0 DMA drained
  f32x4 facc[4][4];
  #pragma unroll
  for (int a = 0; a < 4; ++a)
    #pragma unroll
    for (int b = 0; b < 4; ++b) facc[a][b] = (f32x4){0.f,0.f,0.f,0.f};
  for (int c = 0; c < NCF; ++c) {
    if (c + 1 < NCF)
      stage_f_chunk(c + 1, i0b, j0b, fhh, fhl, Ab[(c + 1) & 1], Bb[(c + 1) & 1], tid);
    compute_chunk(Ab[c & 1], Bb[c & 1], wm, wn, l15, lg, facc);
    __syncthreads();
  }

  float posA[4][4], denA[4][4], posB[4], denB[4];
  #pragma unroll
  for (int mf = 0; mf < 4; ++mf)
    #pragma unroll
    for (int r = 0; r < 4; ++r) { posA[mf][r] = 0.f; denA[mf][r] = 0.f; }
  #pragma unroll
  for (int nf = 0; nf < 4; ++nf) { posB[nf] = 0.f; denB[nf] = 0.f; }

  #pragma unroll
  for (int mf = 0; mf < 4; ++mf)
    #pragma unroll
    for (int nf = 0; nf < 4; ++nf)
      #pragma unroll
      for (int r = 0; r < 4; ++r) {
        float e = __expf(facc[mf][nf][r] * 10.0f);
        denA[mf][r] += e;
        denB[nf] += e;
        u64 bit = 1ull << (mf * 16 + nf * 4 + r);
        if (mA & bit) posA[mf][r] += e;
        if (mB & bit) posB[nf] += e;
      }

  #pragma unroll
  for (int mf = 0; mf < 4; ++mf)
    #pragma unroll
    for (int r = 0; r < 4; ++r) {
      float p = posA[mf][r], d = denA[mf][r];
      #pragma unroll
      for (int off = 1; off < 16; off <<= 1) { p += __shfl_xor(p, off); d += __shfl_xor(d, off); }
      if (l15 == 0) {
        int gi = i0 + mf * 16 + lg * 4 + r;
        atomicAdd(&pos[gi], p);
        atomicAdd(&den[gi], d);
      }
    }
  if (bi != bj) {
    #pragma unroll
    for (int nf = 0; nf < 4; ++nf) {
      float p = posB[nf], d = denB[nf];
      p += __shfl_xor(p, 16); d += __shfl_xor(d, 16);
      p += __shfl_xor(p, 32); d += __shfl_xor(d, 32);
      if (lg == 0) {
        int gj = j0 + nf * 16 + l15;
        atomicAdd(&pos[gj], p);
        atomicAdd(&den[gj], d);
      }
    }
  }
}

__global__ __launch_bounds__(256) void reduce_kernel(const float* __restrict__ pos,
                                                     const float* __restrict__ den,
                                                     float* __restrict__ out) {
  __shared__ float sred[4];
  int t = threadIdx.x;
  float s = 0.f;
  for (int i = t; i < NN; i += 256) s += -logf(pos[i] / den[i]);
  #pragma unroll
  for (int off = 32; off > 0; off >>= 1) s += __shfl_down(s, off);
  if ((t & 63) == 0) sred[t >> 6] = s;
  __syncthreads();
  if (t == 0) out[0] = (sred[0] + sred[1] + sred[2] + sred[3]) * (1.0f / NN);
}

extern "C" void kernel_launch(void* const* d_in, const int* in_sizes, int n_in,
                              void* d_out, int out_size, void* d_ws, size_t ws_size,
                              hipStream_t stream) {
  (void)in_sizes; (void)n_in; (void)out_size; (void)ws_size;
  const float* feat = (const float*)d_in[0];
  const float* cont = (const float*)d_in[1];
  const float* cat  = (const float*)d_in[2];
  const int*   lc   = (const int*)d_in[3];
  float* out = (float*)d_out;

  // ws: fh hi/lo + xc hi/lo (~15.3MB) + 4 vec + simbuf (528*16384 f32 = 34.6MB) ~= 50MB
  ushort_t* fhh = (ushort_t*)d_ws;
  ushort_t* fhl = fhh + (size_t)NN * DF;
  ushort_t* xch = fhl + (size_t)NN * DF;
  ushort_t* xcl = xch + (size_t)NN * KXP;
  float* csq = (float*)(xcl + (size_t)NN * KXP);
  float* rm  = csq + NN;
  float* pos = rm + NN;
  float* den = pos + NN;
  float* simbuf = den + NN;

  prep_kernel<<<NN, 64, 0, stream>>>(feat, cont, cat, fhh, fhl, xch, xcl, csq, rm, pos, den);
  simmax_kernel<<<NTRI, 256, 0, stream>>>(xch, xcl, csq, rm, simbuf, lc);
  loss_kernel<<<NTRI, 256, 0, stream>>>(fhh, fhl, rm, simbuf, pos, den);
  reduce_kernel<<<1, 256, 0, stream>>>(pos, den, out);
}